// Round 1
// baseline (1315.135 us; speedup 1.0000x reference)
//
#include <hip/hip_runtime.h>

typedef __bf16 bf16x8 __attribute__((ext_vector_type(8)));
typedef __bf16 bf16x4 __attribute__((ext_vector_type(4)));
typedef float floatx4 __attribute__((ext_vector_type(4)));

// =====================================================================
// GEMM: C[M,N] = A[M,K] (bf16, row-major, lda) x Bt[N,K]^T (bf16, ldb)
//       (+ optional fp32 bias over N), epilogue fp32 or bf16, ldc stride.
// 128x128 tile, 256 threads = 4 waves, each wave 64x64 via 4x4 MFMA
// 16x16x32 bf16. LDS rows padded to 40 bf16 (2-way bank alias = free).
// M,N multiples of 128; K multiple of 32; lda/ldb multiples of 8.
// =====================================================================
__global__ __launch_bounds__(256)
void gemm_nt(const __bf16* __restrict__ A, const __bf16* __restrict__ Bt,
             const float* __restrict__ bias, void* __restrict__ Cv,
             int K, int lda, int ldb, int ldc, int bf16_out)
{
  __shared__ __align__(16) __bf16 As[128 * 40];
  __shared__ __align__(16) __bf16 Bs[128 * 40];
  const int tid  = threadIdx.x;
  const int bm   = blockIdx.y << 7;
  const int bn   = blockIdx.x << 7;
  const int wave = tid >> 6, lane = tid & 63;
  const int wm = (wave & 1) << 6, wn = (wave >> 1) << 6;
  const int lrow = lane & 15, quad = lane >> 4;
  const int srow = tid >> 2, scol = (tid & 3) << 3;

  const __bf16* Ap = A  + (size_t)(bm + srow) * lda + scol;
  const __bf16* Bp = Bt + (size_t)(bn + srow) * ldb + scol;

  floatx4 acc[4][4];
#pragma unroll
  for (int i = 0; i < 4; ++i)
#pragma unroll
    for (int j = 0; j < 4; ++j) acc[i][j] = floatx4{0.f, 0.f, 0.f, 0.f};

  for (int k0 = 0; k0 < K; k0 += 32) {
    *(bf16x8*)&As[srow * 40 + scol]        = *(const bf16x8*)(Ap + k0);
    *(bf16x8*)&As[(srow + 64) * 40 + scol] = *(const bf16x8*)(Ap + (size_t)64 * lda + k0);
    *(bf16x8*)&Bs[srow * 40 + scol]        = *(const bf16x8*)(Bp + k0);
    *(bf16x8*)&Bs[(srow + 64) * 40 + scol] = *(const bf16x8*)(Bp + (size_t)64 * ldb + k0);
    __syncthreads();
    bf16x8 af[4], bfr[4];
#pragma unroll
    for (int i = 0; i < 4; ++i) {
      af[i]  = *(const bf16x8*)&As[(wm + i * 16 + lrow) * 40 + (quad << 3)];
      bfr[i] = *(const bf16x8*)&Bs[(wn + i * 16 + lrow) * 40 + (quad << 3)];
    }
#pragma unroll
    for (int i = 0; i < 4; ++i)
#pragma unroll
      for (int j = 0; j < 4; ++j)
        acc[i][j] = __builtin_amdgcn_mfma_f32_16x16x32_bf16(af[i], bfr[j], acc[i][j], 0, 0, 0);
    __syncthreads();
  }

  // C/D layout (verified m89/m91): col = lane&15, row = quad*4 + reg
  if (bf16_out) {
    __bf16* C = (__bf16*)Cv;
#pragma unroll
    for (int i = 0; i < 4; ++i) {
      const int row0 = bm + wm + i * 16 + (quad << 2);
#pragma unroll
      for (int j = 0; j < 4; ++j) {
        const int col = bn + wn + j * 16 + lrow;
        const float bv = bias ? bias[col] : 0.f;
#pragma unroll
        for (int r = 0; r < 4; ++r)
          C[(size_t)(row0 + r) * ldc + col] = (__bf16)(acc[i][j][r] + bv);
      }
    }
  } else {
    float* C = (float*)Cv;
#pragma unroll
    for (int i = 0; i < 4; ++i) {
      const int row0 = bm + wm + i * 16 + (quad << 2);
#pragma unroll
      for (int j = 0; j < 4; ++j) {
        const int col = bn + wn + j * 16 + lrow;
        const float bv = bias ? bias[col] : 0.f;
#pragma unroll
        for (int r = 0; r < 4; ++r)
          C[(size_t)(row0 + r) * ldc + col] = acc[i][j][r] + bv;
      }
    }
  }
}

// ------------- fp32 -> bf16 convert, optional scale, strided -------------
__global__ __launch_bounds__(256)
void f2b_kernel(const float* __restrict__ src, __bf16* __restrict__ dst,
                int rows, int cols, int src_ld, int dst_ld, float scale)
{
  int idx = blockIdx.x * 256 + threadIdx.x;
  int cols4 = cols >> 2;
  if (idx >= rows * cols4) return;
  int r = idx / cols4, c = (idx - r * cols4) << 2;
  float4 v = *(const float4*)(src + (size_t)r * src_ld + c);
  bf16x4 o;
  o[0] = (__bf16)(v.x * scale); o[1] = (__bf16)(v.y * scale);
  o[2] = (__bf16)(v.z * scale); o[3] = (__bf16)(v.w * scale);
  *(bf16x4*)(dst + (size_t)r * dst_ld + c) = o;
}

// ------------- fp32 [R,C] -> bf16 [C,R] transpose-convert -------------
__global__ __launch_bounds__(256)
void tconv_kernel(const float* __restrict__ src, __bf16* __restrict__ dst,
                  int R, int C)
{
  __shared__ float tile[32][33];
  const int c0 = blockIdx.x << 5, r0 = blockIdx.y << 5;
  const int x = threadIdx.x & 31, y = threadIdx.x >> 5;  // 32x8
#pragma unroll
  for (int i = 0; i < 32; i += 8)
    tile[y + i][x] = src[(size_t)(r0 + y + i) * C + c0 + x];
  __syncthreads();
#pragma unroll
  for (int i = 0; i < 32; i += 8)
    dst[(size_t)(c0 + y + i) * R + r0 + x] = (__bf16)tile[x][y + i];
}

// ------------- LayerNorm (+scale,bias) + ReLU -> bf16, one block/row -------------
__global__ __launch_bounds__(256)
void ln_relu_kernel(const float* __restrict__ x, const float* __restrict__ sc,
                    const float* __restrict__ bi, __bf16* __restrict__ out, int cols)
{
  const int row = blockIdx.x;
  const float* xr = x + (size_t)row * cols;
  __bf16* orow = out + (size_t)row * cols;
  float s = 0.f, ss = 0.f;
  for (int c = threadIdx.x << 2; c < cols; c += 1024) {
    float4 v = *(const float4*)&xr[c];
    s  += v.x + v.y + v.z + v.w;
    ss += v.x * v.x + v.y * v.y + v.z * v.z + v.w * v.w;
  }
  __shared__ float shs[4], shss[4];
  const int lane = threadIdx.x & 63, w = threadIdx.x >> 6;
  for (int o = 32; o; o >>= 1) { s += __shfl_down(s, o, 64); ss += __shfl_down(ss, o, 64); }
  if (!lane) { shs[w] = s; shss[w] = ss; }
  __syncthreads();
  const float fs = shs[0] + shs[1] + shs[2] + shs[3];
  const float fss = shss[0] + shss[1] + shss[2] + shss[3];
  const float mu = fs / cols;
  const float rstd = rsqrtf(fss / cols - mu * mu + 1e-6f);
  for (int c = threadIdx.x << 2; c < cols; c += 1024) {
    float4 v = *(const float4*)&xr[c];
    float4 scv = *(const float4*)&sc[c];
    float4 biv = *(const float4*)&bi[c];
    bf16x4 o;
    o[0] = (__bf16)fmaxf((v.x - mu) * rstd * scv.x + biv.x, 0.f);
    o[1] = (__bf16)fmaxf((v.y - mu) * rstd * scv.y + biv.y, 0.f);
    o[2] = (__bf16)fmaxf((v.z - mu) * rstd * scv.z + biv.z, 0.f);
    o[3] = (__bf16)fmaxf((v.w - mu) * rstd * scv.w + biv.w, 0.f);
    *(bf16x4*)&orow[c] = o;
  }
}

// ------------- row softmax fp32 -> bf16, one block/row -------------
__global__ __launch_bounds__(256)
void softmax_kernel(const float* __restrict__ x, __bf16* __restrict__ out, int cols)
{
  const int row = blockIdx.x;
  const float* xr = x + (size_t)row * cols;
  __bf16* orow = out + (size_t)row * cols;
  float m = -3.0e38f;
  for (int c = threadIdx.x << 2; c < cols; c += 1024) {
    float4 v = *(const float4*)&xr[c];
    m = fmaxf(m, fmaxf(fmaxf(v.x, v.y), fmaxf(v.z, v.w)));
  }
  __shared__ float sh[4];
  const int lane = threadIdx.x & 63, w = threadIdx.x >> 6;
  for (int o = 32; o; o >>= 1) m = fmaxf(m, __shfl_down(m, o, 64));
  if (!lane) sh[w] = m;
  __syncthreads();
  m = fmaxf(fmaxf(sh[0], sh[1]), fmaxf(sh[2], sh[3]));
  __syncthreads();
  float s = 0.f;
  for (int c = threadIdx.x << 2; c < cols; c += 1024) {
    float4 v = *(const float4*)&xr[c];
    s += expf(v.x - m) + expf(v.y - m) + expf(v.z - m) + expf(v.w - m);
  }
  for (int o = 32; o; o >>= 1) s += __shfl_down(s, o, 64);
  if (!lane) sh[w] = s;
  __syncthreads();
  const float rs = 1.f / (sh[0] + sh[1] + sh[2] + sh[3]);
  for (int c = threadIdx.x << 2; c < cols; c += 1024) {
    float4 v = *(const float4*)&xr[c];
    bf16x4 o;
    o[0] = (__bf16)(expf(v.x - m) * rs); o[1] = (__bf16)(expf(v.y - m) * rs);
    o[2] = (__bf16)(expf(v.z - m) * rs); o[3] = (__bf16)(expf(v.w - m) * rs);
    *(bf16x4*)&orow[c] = o;
  }
}

// ------------- mix = softmax(ctx_cat @ Wmix + bmix), one block/row -------------
__global__ __launch_bounds__(256)
void wmix_kernel(const __bf16* __restrict__ ctx, const float* __restrict__ Wm,
                 const float* __restrict__ bm, float* __restrict__ mix)
{
  const int row = blockIdx.x;
  const __bf16* cr = ctx + (size_t)row * 3072;
  float a0 = 0.f, a1 = 0.f, a2 = 0.f;
  for (int c = threadIdx.x; c < 3072; c += 256) {
    float v = (float)cr[c];
    a0 = fmaf(v, Wm[c * 3 + 0], a0);
    a1 = fmaf(v, Wm[c * 3 + 1], a1);
    a2 = fmaf(v, Wm[c * 3 + 2], a2);
  }
  __shared__ float sh[3][4];
  const int lane = threadIdx.x & 63, w = threadIdx.x >> 6;
  for (int o = 32; o; o >>= 1) {
    a0 += __shfl_down(a0, o, 64); a1 += __shfl_down(a1, o, 64); a2 += __shfl_down(a2, o, 64);
  }
  if (!lane) { sh[0][w] = a0; sh[1][w] = a1; sh[2][w] = a2; }
  __syncthreads();
  if (threadIdx.x == 0) {
    float l0 = sh[0][0] + sh[0][1] + sh[0][2] + sh[0][3] + bm[0];
    float l1 = sh[1][0] + sh[1][1] + sh[1][2] + sh[1][3] + bm[1];
    float l2 = sh[2][0] + sh[2][1] + sh[2][2] + sh[2][3] + bm[2];
    float mm = fmaxf(l0, fmaxf(l1, l2));
    float e0 = expf(l0 - mm), e1 = expf(l1 - mm), e2 = expf(l2 - mm);
    float rs = 1.f / (e0 + e1 + e2);
    mix[row * 4 + 0] = e0 * rs; mix[row * 4 + 1] = e1 * rs; mix[row * 4 + 2] = e2 * rs;
  }
}

// ------------- c_t = sum_l mix[l]*ctx_l -> bf16 into 3 concat buffers -------------
__global__ __launch_bounds__(256)
void ct_combine_kernel(const __bf16* __restrict__ ctx, const float* __restrict__ mix,
                       __bf16* __restrict__ cz, __bf16* __restrict__ pc,
                       __bf16* __restrict__ sec)
{
  const int idx = blockIdx.x * 256 + threadIdx.x;  // 2048*1024 exact
  const int row = idx >> 10, d = idx & 1023;
  const __bf16* cr = ctx + (size_t)row * 3072 + d;
  const float v = mix[row * 4 + 0] * (float)cr[0] +
                  mix[row * 4 + 1] * (float)cr[1024] +
                  mix[row * 4 + 2] * (float)cr[2048];
  const __bf16 b = (__bf16)v;
  cz[(size_t)row * 2048 + d] = b;
  pc[(size_t)row * 2048 + 1024 + d] = b;
  sec[(size_t)row * 3072 + 2048 + d] = b;
}

// ------------- w_t = tanh(amod)*(tanh(A_diag)*0.9*w_prev + uv) + wB -------------
__global__ __launch_bounds__(256)
void w_combine_kernel(const float* __restrict__ w_prev, const float* __restrict__ uv,
                      const float* __restrict__ amod, const float* __restrict__ wB,
                      const float* __restrict__ A_diag, float* __restrict__ w_out,
                      __bf16* __restrict__ w_bf)
{
  const int idx = blockIdx.x * 256 + threadIdx.x;  // 2048*512 exact
  const int d = idx & 511;
  const float Ad = tanhf(A_diag[d]) * 0.9f;
  const float wl = fmaf(Ad, w_prev[idx], uv[idx]);
  const float w = fmaf(tanhf(amod[idx]), wl, wB[idx]);
  w_out[idx] = w;
  w_bf[idx] = (__bf16)w;
}

// ------------- p_t = p_prev + mlp_out -------------
__global__ __launch_bounds__(256)
void p_combine_kernel(const float* __restrict__ p_prev, const float* __restrict__ hp,
                      float* __restrict__ p_out, __bf16* __restrict__ p_bf)
{
  const int idx = blockIdx.x * 256 + threadIdx.x;  // 2048*1024 exact
  const float p = p_prev[idx] + hp[idx];
  p_out[idx] = p;
  p_bf[idx] = (__bf16)p;
}

// ------------- s_t = clip(s_prev + g*pu + (1-g)*wu, +-10) -------------
__global__ __launch_bounds__(256)
void s_final_kernel(const float* __restrict__ s_prev, const float* __restrict__ gpre,
                    const float* __restrict__ pu, const float* __restrict__ wu,
                    float* __restrict__ s_out)
{
  const int idx = blockIdx.x * 256 + threadIdx.x;  // 2048*1024 exact
  const float g = 1.f / (1.f + expf(-gpre[idx]));
  float s = s_prev[idx] + g * pu[idx] + (1.f - g) * wu[idx];
  s = fminf(fmaxf(s, -10.f), 10.f);
  s_out[idx] = s;
}

// =====================================================================
extern "C" void kernel_launch(void* const* d_in, const int* in_sizes, int n_in,
                              void* d_out, int out_size, void* d_ws, size_t ws_size,
                              hipStream_t stream)
{
  const float* s_prev   = (const float*)d_in[0];
  const float* w_prev   = (const float*)d_in[1];
  const float* p_prev   = (const float*)d_in[2];
  const float* e_t      = (const float*)d_in[3];
  const float* M0       = (const float*)d_in[4];
  const float* M1       = (const float*)d_in[5];
  const float* M2       = (const float*)d_in[6];
  const float* K0       = (const float*)d_in[7];
  const float* K1       = (const float*)d_in[8];
  const float* K2       = (const float*)d_in[9];
  const float* Wq1      = (const float*)d_in[10];
  const float* bq1      = (const float*)d_in[11];
  const float* lnq_s    = (const float*)d_in[12];
  const float* lnq_b    = (const float*)d_in[13];
  const float* Wq2      = (const float*)d_in[14];
  const float* bq2      = (const float*)d_in[15];
  const float* Wl0      = (const float*)d_in[16];
  const float* Wl1      = (const float*)d_in[17];
  const float* Wl2      = (const float*)d_in[18];
  const float* Wmix     = (const float*)d_in[19];
  const float* bmix     = (const float*)d_in[20];
  const float* Wz       = (const float*)d_in[21];
  const float* bz       = (const float*)d_in[22];
  const float* A_diag   = (const float*)d_in[23];
  const float* A_U      = (const float*)d_in[24];
  const float* A_V      = (const float*)d_in[25];
  const float* Wamod    = (const float*)d_in[26];
  const float* bamod    = (const float*)d_in[27];
  const float* WB_w     = (const float*)d_in[28];
  const float* bB       = (const float*)d_in[29];
  const float* Wp1      = (const float*)d_in[30];
  const float* bp1      = (const float*)d_in[31];
  const float* lnp_s    = (const float*)d_in[32];
  const float* lnp_b    = (const float*)d_in[33];
  const float* Wp2      = (const float*)d_in[34];
  const float* bp2      = (const float*)d_in[35];
  const float* Wg       = (const float*)d_in[36];
  const float* bg       = (const float*)d_in[37];
  const float* U_p      = (const float*)d_in[38];
  const float* U_w      = (const float*)d_in[39];

  float* out_s = (float*)d_out;                 // [2048,1024]
  float* out_w = out_s + 2048 * 1024;           // [2048, 512]
  float* out_p = out_w + 2048 * 512;            // [2048,1024]

  char* base = (char*)d_ws;
  size_t off = 0;
  auto alloc = [&](size_t n) -> void* {
    void* p = base + off;
    off = (off + n + 255) & ~(size_t)255;
    return p;
  };

  // bf16 weights ([N,K] layout for NT gemm) ---- ~75 MB
  __bf16* Wq1t   = (__bf16*)alloc((size_t)2048 * 2048 * 2);
  __bf16* Wq2t   = (__bf16*)alloc((size_t)256 * 2048 * 2);
  __bf16* Kb0    = (__bf16*)alloc((size_t)4096 * 256 * 2);
  __bf16* Kb1    = (__bf16*)alloc((size_t)4096 * 256 * 2);
  __bf16* Kb2    = (__bf16*)alloc((size_t)4096 * 256 * 2);
  __bf16* Mt0    = (__bf16*)alloc((size_t)1024 * 4096 * 2);
  __bf16* Mt1    = (__bf16*)alloc((size_t)1024 * 4096 * 2);
  __bf16* Mt2    = (__bf16*)alloc((size_t)1024 * 4096 * 2);
  __bf16* Wlt0   = (__bf16*)alloc((size_t)1024 * 1024 * 2);
  __bf16* Wlt1   = (__bf16*)alloc((size_t)1024 * 1024 * 2);
  __bf16* Wlt2   = (__bf16*)alloc((size_t)1024 * 1024 * 2);
  __bf16* Wzt    = (__bf16*)alloc((size_t)1024 * 1024 * 2);
  __bf16* AVt    = (__bf16*)alloc((size_t)128 * 512 * 2);
  __bf16* AUb    = (__bf16*)alloc((size_t)512 * 128 * 2);
  __bf16* Wamodt = (__bf16*)alloc((size_t)512 * 1024 * 2);
  __bf16* WBt    = (__bf16*)alloc((size_t)512 * 2048 * 2);
  __bf16* Wp1t   = (__bf16*)alloc((size_t)2048 * 2048 * 2);
  __bf16* Wp2t   = (__bf16*)alloc((size_t)1024 * 2048 * 2);
  __bf16* Wgt    = (__bf16*)alloc((size_t)1024 * 3072 * 2);
  __bf16* Upb    = (__bf16*)alloc((size_t)1024 * 1024 * 2);
  __bf16* Uwb    = (__bf16*)alloc((size_t)1024 * 512 * 2);
  // activations ---- ~190 MB
  __bf16* cat_se  = (__bf16*)alloc((size_t)2048 * 2048 * 2);
  float*  tmp1    = (float*)alloc((size_t)2048 * 2048 * 4);
  __bf16* hq      = (__bf16*)alloc((size_t)2048 * 2048 * 2);   // q_ln / h reuse
  float*  qtmp    = (float*)alloc((size_t)2048 * 256 * 4);
  __bf16* qb      = (__bf16*)alloc((size_t)2048 * 256 * 2);
  float*  scores  = (float*)alloc((size_t)2048 * 4096 * 4);
  __bf16* attn    = (__bf16*)alloc((size_t)2048 * 4096 * 2);
  __bf16* amb     = (__bf16*)alloc((size_t)2048 * 1024 * 2);
  __bf16* ctxcat  = (__bf16*)alloc((size_t)2048 * 3072 * 2);
  float*  mix     = (float*)alloc((size_t)2048 * 4 * 4);
  __bf16* cat_cz  = (__bf16*)alloc((size_t)2048 * 2048 * 2);
  __bf16* cat_pc  = (__bf16*)alloc((size_t)2048 * 2048 * 2);
  __bf16* cat_sec = (__bf16*)alloc((size_t)2048 * 3072 * 2);
  __bf16* wpb     = (__bf16*)alloc((size_t)2048 * 512 * 2);
  float*  uvt     = (float*)alloc((size_t)2048 * 128 * 4);
  __bf16* uvtb    = (__bf16*)alloc((size_t)2048 * 128 * 2);
  float*  uv      = (float*)alloc((size_t)2048 * 512 * 4);
  float*  amod    = (float*)alloc((size_t)2048 * 512 * 4);
  float*  wBo     = (float*)alloc((size_t)2048 * 512 * 4);
  __bf16* wtb     = (__bf16*)alloc((size_t)2048 * 512 * 2);
  float*  hp      = (float*)alloc((size_t)2048 * 1024 * 4);
  __bf16* ptb     = (__bf16*)alloc((size_t)2048 * 1024 * 2);
  float*  gpre    = (float*)alloc((size_t)2048 * 1024 * 4);
  float*  pu      = (float*)alloc((size_t)2048 * 1024 * 4);
  float*  wu      = (float*)alloc((size_t)2048 * 1024 * 4);

  auto gemm = [&](const __bf16* Ap, const __bf16* Bp, const float* bias, void* C,
                  int M, int N, int K, int lda, int ldb, int ldc, int bf16o) {
    dim3 g(N >> 7, M >> 7);
    gemm_nt<<<g, 256, 0, stream>>>(Ap, Bp, bias, C, K, lda, ldb, ldc, bf16o);
  };
  auto tconv = [&](const float* s, __bf16* d, int R, int C) {
    dim3 g(C >> 5, R >> 5);
    tconv_kernel<<<g, 256, 0, stream>>>(s, d, R, C);
  };
  auto f2b = [&](const float* s, __bf16* d, int rows, int cols, int sld, int dld,
                 float sc) {
    int n = rows * (cols >> 2);
    f2b_kernel<<<(n + 255) / 256, 256, 0, stream>>>(s, d, rows, cols, sld, dld, sc);
  };

  // ---- weight conversions ----
  tconv(Wq1, Wq1t, 2048, 2048);
  tconv(Wq2, Wq2t, 2048, 256);
  f2b(K0, Kb0, 1, 4096 * 256, 0, 0, 1.f);
  f2b(K1, Kb1, 1, 4096 * 256, 0, 0, 1.f);
  f2b(K2, Kb2, 1, 4096 * 256, 0, 0, 1.f);
  tconv(M0, Mt0, 4096, 1024);
  tconv(M1, Mt1, 4096, 1024);
  tconv(M2, Mt2, 4096, 1024);
  tconv(Wl0, Wlt0, 1024, 1024);
  tconv(Wl1, Wlt1, 1024, 1024);
  tconv(Wl2, Wlt2, 1024, 1024);
  tconv(Wz, Wzt, 1024, 1024);
  tconv(A_V, AVt, 512, 128);
  f2b(A_U, AUb, 1, 512 * 128, 0, 0, 1.f);
  tconv(Wamod, Wamodt, 1024, 512);
  tconv(WB_w, WBt, 2048, 512);
  tconv(Wp1, Wp1t, 2048, 2048);
  tconv(Wp2, Wp2t, 2048, 1024);
  tconv(Wg, Wgt, 3072, 1024);
  f2b(U_p, Upb, 1, 1024 * 1024, 0, 0, 1.f);
  f2b(U_w, Uwb, 1, 1024 * 512, 0, 0, 1.f);
  // ---- activation concats ----
  f2b(s_prev, cat_se, 2048, 1024, 1024, 2048, 1.f);
  f2b(e_t, cat_se + 1024, 2048, 1024, 1024, 2048, 1.f);
  f2b(p_prev, cat_pc, 2048, 1024, 1024, 2048, 1.f);
  f2b(s_prev, cat_sec, 2048, 1024, 1024, 3072, 1.f);
  f2b(e_t, cat_sec + 1024, 2048, 1024, 1024, 3072, 1.f);
  f2b(w_prev, wpb, 1, 2048 * 512, 0, 0, 1.f);

  // ---- q path ----
  gemm(cat_se, Wq1t, bq1, tmp1, 2048, 2048, 2048, 2048, 2048, 2048, 0);
  ln_relu_kernel<<<2048, 256, 0, stream>>>(tmp1, lnq_s, lnq_b, hq, 2048);
  gemm(hq, Wq2t, bq2, qtmp, 2048, 256, 2048, 2048, 2048, 256, 0);
  f2b(qtmp, qb, 1, 2048 * 256, 0, 0, 0.0625f);  // fold 1/sqrt(256) into q

  // ---- CMS levels ----
  const __bf16* Kbs[3] = {Kb0, Kb1, Kb2};
  const __bf16* Mts[3] = {Mt0, Mt1, Mt2};
  const __bf16* Wlts[3] = {Wlt0, Wlt1, Wlt2};
  for (int l = 0; l < 3; ++l) {
    gemm(qb, Kbs[l], nullptr, scores, 2048, 4096, 256, 256, 256, 4096, 0);
    softmax_kernel<<<2048, 256, 0, stream>>>(scores, attn, 4096);
    gemm(attn, Mts[l], nullptr, amb, 2048, 1024, 4096, 4096, 4096, 1024, 1);
    gemm(amb, Wlts[l], nullptr, ctxcat + l * 1024, 2048, 1024, 1024, 1024, 1024, 3072, 1);
  }
  wmix_kernel<<<2048, 256, 0, stream>>>(ctxcat, Wmix, bmix, mix);
  ct_combine_kernel<<<8192, 256, 0, stream>>>(ctxcat, mix, cat_cz, cat_pc, cat_sec);

  // ---- wave path ----
  gemm(cat_se + 1024, Wzt, bz, cat_cz + 1024, 2048, 1024, 1024, 2048, 1024, 2048, 1);
  gemm(wpb, AVt, nullptr, uvt, 2048, 128, 512, 512, 512, 128, 0);
  f2b(uvt, uvtb, 1, 2048 * 128, 0, 0, 1.f);
  gemm(uvtb, AUb, nullptr, uv, 2048, 512, 128, 128, 128, 512, 0);
  gemm(cat_cz, Wamodt, bamod, amod, 2048, 512, 1024, 2048, 1024, 512, 0);
  gemm(cat_cz, WBt, bB, wBo, 2048, 512, 2048, 2048, 2048, 512, 0);
  w_combine_kernel<<<4096, 256, 0, stream>>>(w_prev, uv, amod, wBo, A_diag, out_w, wtb);

  // ---- particle path ----
  gemm(cat_pc, Wp1t, bp1, tmp1, 2048, 2048, 2048, 2048, 2048, 2048, 0);
  ln_relu_kernel<<<2048, 256, 0, stream>>>(tmp1, lnp_s, lnp_b, hq, 2048);
  gemm(hq, Wp2t, bp2, hp, 2048, 1024, 2048, 2048, 2048, 1024, 0);
  p_combine_kernel<<<8192, 256, 0, stream>>>(p_prev, hp, out_p, ptb);

  // ---- gate + final state ----
  gemm(cat_sec, Wgt, bg, gpre, 2048, 1024, 3072, 3072, 3072, 1024, 0);
  gemm(ptb, Upb, nullptr, pu, 2048, 1024, 1024, 1024, 1024, 1024, 0);
  gemm(wtb, Uwb, nullptr, wu, 2048, 1024, 512, 512, 512, 1024, 0);
  s_final_kernel<<<8192, 256, 0, stream>>>(s_prev, gpre, pu, wu, out_s);
}

// Round 2
// 959.277 us; speedup vs baseline: 1.3710x; 1.3710x over previous
//
#include <hip/hip_runtime.h>

typedef __bf16 bf16x8 __attribute__((ext_vector_type(8)));
typedef __bf16 bf16x4 __attribute__((ext_vector_type(4)));
typedef float floatx4 __attribute__((ext_vector_type(4)));

__device__ __forceinline__ void gl_lds16(const __bf16* g, const __bf16* l) {
  __builtin_amdgcn_global_load_lds(
      (const __attribute__((address_space(1))) unsigned int*)g,
      (__attribute__((address_space(3))) unsigned int*)l, 16, 0, 0);
}

// =====================================================================
// GEMM: C[M,N] = A[M,K] bf16 row-major (lda) x Bt[N,K]^T bf16 (ldb)
//       + optional fp32 bias over N, * cscale, epilogue fp32 or bf16.
// Batched via blockIdx.z with element strides sA/sB/sC.
// BMxBN tile, 256 threads = 4 waves (2x2), wave tile (BM/2)x(BN/2),
// 16x16x32 bf16 MFMA. Staging via global_load_lds width=16 (m97 layout:
// unpadded LDS, row stride 32 bf16 = 64B; lane order == LDS order).
// M%BM==0, N%BN==0, K%32==0, lda/ldb%8==0.
// =====================================================================
template <int BM, int BN>
__global__ __launch_bounds__(256)
void gemm_nt(const __bf16* __restrict__ A, const __bf16* __restrict__ Bt,
             const float* __restrict__ bias, void* __restrict__ Cv,
             int K, int lda, int ldb, int ldc, int bf16_out, float cscale,
             long sA, long sB, long sC)
{
  constexpr int MI = BM / 32;   // per-wave MFMA tiles in M
  constexpr int NJ = BN / 32;   // per-wave MFMA tiles in N
  __shared__ __align__(16) __bf16 As[BM * 32];
  __shared__ __align__(16) __bf16 Bs[BN * 32];
  const int tid = threadIdx.x;
  const int bm = blockIdx.y * BM, bn = blockIdx.x * BN;
  const __bf16* Ab = A  + (size_t)blockIdx.z * sA;
  const __bf16* Bb = Bt + (size_t)blockIdx.z * sB;
  const int wave = tid >> 6, lane = tid & 63;
  const int wm = (wave & 1) * (BM / 2), wn = (wave >> 1) * (BN / 2);
  const int lrow = lane & 15, quad = lane >> 4;
  const int srow = tid >> 2, scol = (tid & 3) << 3;  // staging: 4 thr/row

  const __bf16* Ap = Ab + (size_t)(bm + srow) * lda + scol;
  const __bf16* Bp = Bb + (size_t)(bn + srow) * ldb + scol;

  floatx4 acc[MI][NJ];
#pragma unroll
  for (int i = 0; i < MI; ++i)
#pragma unroll
    for (int j = 0; j < NJ; ++j) acc[i][j] = floatx4{0.f, 0.f, 0.f, 0.f};

  for (int k0 = 0; k0 < K; k0 += 32) {
#pragma unroll
    for (int r = 0; r < BM / 64; ++r)
      gl_lds16(Ap + (size_t)(64 * r) * lda + k0, &As[tid * 8 + r * 2048]);
#pragma unroll
    for (int r = 0; r < BN / 64; ++r)
      gl_lds16(Bp + (size_t)(64 * r) * ldb + k0, &Bs[tid * 8 + r * 2048]);
    __syncthreads();
    bf16x8 af[MI], bfr[NJ];
#pragma unroll
    for (int i = 0; i < MI; ++i)
      af[i] = *(const bf16x8*)&As[(wm + i * 16 + lrow) * 32 + (quad << 3)];
#pragma unroll
    for (int j = 0; j < NJ; ++j)
      bfr[j] = *(const bf16x8*)&Bs[(wn + j * 16 + lrow) * 32 + (quad << 3)];
#pragma unroll
    for (int i = 0; i < MI; ++i)
#pragma unroll
      for (int j = 0; j < NJ; ++j)
        acc[i][j] = __builtin_amdgcn_mfma_f32_16x16x32_bf16(af[i], bfr[j], acc[i][j], 0, 0, 0);
    __syncthreads();
  }

  // C/D layout (verified m89/m91): col = lane&15, row = quad*4 + reg
  if (bf16_out) {
    __bf16* C = (__bf16*)Cv + (size_t)blockIdx.z * sC;
#pragma unroll
    for (int i = 0; i < MI; ++i) {
      const int row0 = bm + wm + i * 16 + (quad << 2);
#pragma unroll
      for (int j = 0; j < NJ; ++j) {
        const int col = bn + wn + j * 16 + lrow;
        const float bv = bias ? bias[col] : 0.f;
#pragma unroll
        for (int r = 0; r < 4; ++r)
          C[(size_t)(row0 + r) * ldc + col] = (__bf16)((acc[i][j][r] + bv) * cscale);
      }
    }
  } else {
    float* C = (float*)Cv + (size_t)blockIdx.z * sC;
#pragma unroll
    for (int i = 0; i < MI; ++i) {
      const int row0 = bm + wm + i * 16 + (quad << 2);
#pragma unroll
      for (int j = 0; j < NJ; ++j) {
        const int col = bn + wn + j * 16 + lrow;
        const float bv = bias ? bias[col] : 0.f;
#pragma unroll
        for (int r = 0; r < 4; ++r)
          C[(size_t)(row0 + r) * ldc + col] = (acc[i][j][r] + bv) * cscale;
      }
    }
  }
}

// ------------- fp32 -> bf16 convert, strided -------------
__global__ __launch_bounds__(256)
void f2b_kernel(const float* __restrict__ src, __bf16* __restrict__ dst,
                int rows, int cols, int src_ld, int dst_ld)
{
  int idx = blockIdx.x * 256 + threadIdx.x;
  int cols4 = cols >> 2;
  if (idx >= rows * cols4) return;
  int r = idx / cols4, c = (idx - r * cols4) << 2;
  float4 v = *(const float4*)(src + (size_t)r * src_ld + c);
  bf16x4 o;
  o[0] = (__bf16)v.x; o[1] = (__bf16)v.y; o[2] = (__bf16)v.z; o[3] = (__bf16)v.w;
  *(bf16x4*)(dst + (size_t)r * dst_ld + c) = o;
}

// ------------- fp32 [R,C] -> bf16 [C,R] transpose-convert -------------
__global__ __launch_bounds__(256)
void tconv_kernel(const float* __restrict__ src, __bf16* __restrict__ dst,
                  int R, int C)
{
  __shared__ float tile[32][33];
  const int c0 = blockIdx.x << 5, r0 = blockIdx.y << 5;
  const int x = threadIdx.x & 31, y = threadIdx.x >> 5;  // 32x8
#pragma unroll
  for (int i = 0; i < 32; i += 8)
    tile[y + i][x] = src[(size_t)(r0 + y + i) * C + c0 + x];
  __syncthreads();
#pragma unroll
  for (int i = 0; i < 32; i += 8)
    dst[(size_t)(c0 + y + i) * R + r0 + x] = (__bf16)tile[x][y + i];
}

// ------------- LayerNorm (+scale,bias) + ReLU -> bf16, one block/row -------------
__global__ __launch_bounds__(256)
void ln_relu_kernel(const float* __restrict__ x, const float* __restrict__ sc,
                    const float* __restrict__ bi, __bf16* __restrict__ out, int cols)
{
  const int row = blockIdx.x;
  const float* xr = x + (size_t)row * cols;
  __bf16* orow = out + (size_t)row * cols;
  float s = 0.f, ss = 0.f;
  for (int c = threadIdx.x << 2; c < cols; c += 1024) {
    float4 v = *(const float4*)&xr[c];
    s  += v.x + v.y + v.z + v.w;
    ss += v.x * v.x + v.y * v.y + v.z * v.z + v.w * v.w;
  }
  __shared__ float shs[4], shss[4];
  const int lane = threadIdx.x & 63, w = threadIdx.x >> 6;
  for (int o = 32; o; o >>= 1) { s += __shfl_down(s, o, 64); ss += __shfl_down(ss, o, 64); }
  if (!lane) { shs[w] = s; shss[w] = ss; }
  __syncthreads();
  const float fs = shs[0] + shs[1] + shs[2] + shs[3];
  const float fss = shss[0] + shss[1] + shss[2] + shss[3];
  const float mu = fs / cols;
  const float rstd = rsqrtf(fss / cols - mu * mu + 1e-6f);
  for (int c = threadIdx.x << 2; c < cols; c += 1024) {
    float4 v = *(const float4*)&xr[c];
    float4 scv = *(const float4*)&sc[c];
    float4 biv = *(const float4*)&bi[c];
    bf16x4 o;
    o[0] = (__bf16)fmaxf((v.x - mu) * rstd * scv.x + biv.x, 0.f);
    o[1] = (__bf16)fmaxf((v.y - mu) * rstd * scv.y + biv.y, 0.f);
    o[2] = (__bf16)fmaxf((v.z - mu) * rstd * scv.z + biv.z, 0.f);
    o[3] = (__bf16)fmaxf((v.w - mu) * rstd * scv.w + biv.w, 0.f);
    *(bf16x4*)&orow[c] = o;
  }
}

// ------------- in-place row softmax on bf16, cols=4096, 16 elems/thread -------------
__global__ __launch_bounds__(256)
void softmax_bf16_kernel(__bf16* __restrict__ x)
{
  __bf16* xr = x + (size_t)blockIdx.x * 4096;
  bf16x8 v0 = *(const bf16x8*)&xr[threadIdx.x * 16];
  bf16x8 v1 = *(const bf16x8*)&xr[threadIdx.x * 16 + 8];
  float f[16];
#pragma unroll
  for (int i = 0; i < 8; ++i) { f[i] = (float)v0[i]; f[i + 8] = (float)v1[i]; }
  float m = f[0];
#pragma unroll
  for (int i = 1; i < 16; ++i) m = fmaxf(m, f[i]);
  __shared__ float sh[4];
  const int lane = threadIdx.x & 63, w = threadIdx.x >> 6;
  for (int o = 32; o; o >>= 1) m = fmaxf(m, __shfl_down(m, o, 64));
  if (!lane) sh[w] = m;
  __syncthreads();
  m = fmaxf(fmaxf(sh[0], sh[1]), fmaxf(sh[2], sh[3]));
  __syncthreads();
  float s = 0.f;
#pragma unroll
  for (int i = 0; i < 16; ++i) { f[i] = expf(f[i] - m); s += f[i]; }
  for (int o = 32; o; o >>= 1) s += __shfl_down(s, o, 64);
  if (!lane) sh[w] = s;
  __syncthreads();
  const float rs = 1.f / (sh[0] + sh[1] + sh[2] + sh[3]);
  bf16x8 o0, o1;
#pragma unroll
  for (int i = 0; i < 8; ++i) {
    o0[i] = (__bf16)(f[i] * rs); o1[i] = (__bf16)(f[i + 8] * rs);
  }
  *(bf16x8*)&xr[threadIdx.x * 16] = o0;
  *(bf16x8*)&xr[threadIdx.x * 16 + 8] = o1;
}

// ------------- mix = softmax(ctx_cat @ Wmix + bmix), one block/row -------------
__global__ __launch_bounds__(256)
void wmix_kernel(const __bf16* __restrict__ ctx, const float* __restrict__ Wm,
                 const float* __restrict__ bm, float* __restrict__ mix)
{
  const int row = blockIdx.x;
  const __bf16* cr = ctx + (size_t)row * 3072;
  float a0 = 0.f, a1 = 0.f, a2 = 0.f;
  for (int c = threadIdx.x; c < 3072; c += 256) {
    float v = (float)cr[c];
    a0 = fmaf(v, Wm[c * 3 + 0], a0);
    a1 = fmaf(v, Wm[c * 3 + 1], a1);
    a2 = fmaf(v, Wm[c * 3 + 2], a2);
  }
  __shared__ float sh[3][4];
  const int lane = threadIdx.x & 63, w = threadIdx.x >> 6;
  for (int o = 32; o; o >>= 1) {
    a0 += __shfl_down(a0, o, 64); a1 += __shfl_down(a1, o, 64); a2 += __shfl_down(a2, o, 64);
  }
  if (!lane) { sh[0][w] = a0; sh[1][w] = a1; sh[2][w] = a2; }
  __syncthreads();
  if (threadIdx.x == 0) {
    float l0 = sh[0][0] + sh[0][1] + sh[0][2] + sh[0][3] + bm[0];
    float l1 = sh[1][0] + sh[1][1] + sh[1][2] + sh[1][3] + bm[1];
    float l2 = sh[2][0] + sh[2][1] + sh[2][2] + sh[2][3] + bm[2];
    float mm = fmaxf(l0, fmaxf(l1, l2));
    float e0 = expf(l0 - mm), e1 = expf(l1 - mm), e2 = expf(l2 - mm);
    float rs = 1.f / (e0 + e1 + e2);
    mix[row * 4 + 0] = e0 * rs; mix[row * 4 + 1] = e1 * rs; mix[row * 4 + 2] = e2 * rs;
  }
}

// ------------- c_t = sum_l mix[l]*ctx_l -> bf16 into 3 concat buffers -------------
__global__ __launch_bounds__(256)
void ct_combine_kernel(const __bf16* __restrict__ ctx, const float* __restrict__ mix,
                       __bf16* __restrict__ cz, __bf16* __restrict__ pc,
                       __bf16* __restrict__ sec)
{
  const int idx = blockIdx.x * 256 + threadIdx.x;  // 2048*1024 exact
  const int row = idx >> 10, d = idx & 1023;
  const __bf16* cr = ctx + (size_t)row * 3072 + d;
  const float v = mix[row * 4 + 0] * (float)cr[0] +
                  mix[row * 4 + 1] * (float)cr[1024] +
                  mix[row * 4 + 2] * (float)cr[2048];
  const __bf16 b = (__bf16)v;
  cz[(size_t)row * 2048 + d] = b;
  pc[(size_t)row * 2048 + 1024 + d] = b;
  sec[(size_t)row * 3072 + 2048 + d] = b;
}

// ------------- w_t = tanh(amod)*(tanh(A_diag)*0.9*w_prev + uv) + wB -------------
__global__ __launch_bounds__(256)
void w_combine_kernel(const float* __restrict__ w_prev, const float* __restrict__ uv,
                      const float* __restrict__ amod, const float* __restrict__ wB,
                      const float* __restrict__ A_diag, float* __restrict__ w_out,
                      __bf16* __restrict__ w_bf)
{
  const int idx = blockIdx.x * 256 + threadIdx.x;  // 2048*512 exact
  const int d = idx & 511;
  const float Ad = tanhf(A_diag[d]) * 0.9f;
  const float wl = fmaf(Ad, w_prev[idx], uv[idx]);
  const float w = fmaf(tanhf(amod[idx]), wl, wB[idx]);
  w_out[idx] = w;
  w_bf[idx] = (__bf16)w;
}

// ------------- p_t = p_prev + mlp_out -------------
__global__ __launch_bounds__(256)
void p_combine_kernel(const float* __restrict__ p_prev, const float* __restrict__ hp,
                      float* __restrict__ p_out, __bf16* __restrict__ p_bf)
{
  const int idx = blockIdx.x * 256 + threadIdx.x;  // 2048*1024 exact
  const float p = p_prev[idx] + hp[idx];
  p_out[idx] = p;
  p_bf[idx] = (__bf16)p;
}

// ------------- s_t = clip(s_prev + g*pu + (1-g)*wu, +-10) -------------
__global__ __launch_bounds__(256)
void s_final_kernel(const float* __restrict__ s_prev, const float* __restrict__ gpre,
                    const float* __restrict__ pu, const float* __restrict__ wu,
                    float* __restrict__ s_out)
{
  const int idx = blockIdx.x * 256 + threadIdx.x;  // 2048*1024 exact
  const float g = 1.f / (1.f + expf(-gpre[idx]));
  float s = s_prev[idx] + g * pu[idx] + (1.f - g) * wu[idx];
  s = fminf(fmaxf(s, -10.f), 10.f);
  s_out[idx] = s;
}

// =====================================================================
extern "C" void kernel_launch(void* const* d_in, const int* in_sizes, int n_in,
                              void* d_out, int out_size, void* d_ws, size_t ws_size,
                              hipStream_t stream)
{
  const float* s_prev   = (const float*)d_in[0];
  const float* w_prev   = (const float*)d_in[1];
  const float* p_prev   = (const float*)d_in[2];
  const float* e_t      = (const float*)d_in[3];
  const float* M0       = (const float*)d_in[4];
  const float* M1       = (const float*)d_in[5];
  const float* M2       = (const float*)d_in[6];
  const float* K0       = (const float*)d_in[7];
  const float* K1       = (const float*)d_in[8];
  const float* K2       = (const float*)d_in[9];
  const float* Wq1      = (const float*)d_in[10];
  const float* bq1      = (const float*)d_in[11];
  const float* lnq_s    = (const float*)d_in[12];
  const float* lnq_b    = (const float*)d_in[13];
  const float* Wq2      = (const float*)d_in[14];
  const float* bq2      = (const float*)d_in[15];
  const float* Wl0      = (const float*)d_in[16];
  const float* Wl1      = (const float*)d_in[17];
  const float* Wl2      = (const float*)d_in[18];
  const float* Wmix     = (const float*)d_in[19];
  const float* bmix     = (const float*)d_in[20];
  const float* Wz       = (const float*)d_in[21];
  const float* bz       = (const float*)d_in[22];
  const float* A_diag   = (const float*)d_in[23];
  const float* A_U      = (const float*)d_in[24];
  const float* A_V      = (const float*)d_in[25];
  const float* Wamod    = (const float*)d_in[26];
  const float* bamod    = (const float*)d_in[27];
  const float* WB_w     = (const float*)d_in[28];
  const float* bB       = (const float*)d_in[29];
  const float* Wp1      = (const float*)d_in[30];
  const float* bp1      = (const float*)d_in[31];
  const float* lnp_s    = (const float*)d_in[32];
  const float* lnp_b    = (const float*)d_in[33];
  const float* Wp2      = (const float*)d_in[34];
  const float* bp2      = (const float*)d_in[35];
  const float* Wg       = (const float*)d_in[36];
  const float* bg       = (const float*)d_in[37];
  const float* U_p      = (const float*)d_in[38];
  const float* U_w      = (const float*)d_in[39];

  float* out_s = (float*)d_out;                 // [2048,1024]
  float* out_w = out_s + 2048 * 1024;           // [2048, 512]
  float* out_p = out_w + 2048 * 512;            // [2048,1024]

  char* base = (char*)d_ws;
  size_t off = 0;
  auto alloc = [&](size_t n) -> void* {
    void* p = base + off;
    off = (off + n + 255) & ~(size_t)255;
    return p;
  };

  // bf16 weights ([N,K] layout for NT gemm) ---- ~71 MB
  __bf16* Wq1t   = (__bf16*)alloc((size_t)2048 * 2048 * 2);
  __bf16* Wq2t   = (__bf16*)alloc((size_t)256 * 2048 * 2);
  __bf16* Kb     = (__bf16*)alloc((size_t)3 * 4096 * 256 * 2);   // [3][4096,256]
  __bf16* Mt     = (__bf16*)alloc((size_t)3 * 1024 * 4096 * 2);  // [3][1024,4096]
  __bf16* Wlt    = (__bf16*)alloc((size_t)3 * 1024 * 1024 * 2);  // [3][1024,1024]
  __bf16* Wzt    = (__bf16*)alloc((size_t)1024 * 1024 * 2);
  __bf16* AVt    = (__bf16*)alloc((size_t)128 * 512 * 2);
  __bf16* AUb    = (__bf16*)alloc((size_t)512 * 128 * 2);
  __bf16* Wamodt = (__bf16*)alloc((size_t)512 * 1024 * 2);
  __bf16* WBt    = (__bf16*)alloc((size_t)512 * 2048 * 2);
  __bf16* Wp1t   = (__bf16*)alloc((size_t)2048 * 2048 * 2);
  __bf16* Wp2t   = (__bf16*)alloc((size_t)1024 * 2048 * 2);
  __bf16* Wgt    = (__bf16*)alloc((size_t)1024 * 3072 * 2);
  __bf16* Upb    = (__bf16*)alloc((size_t)1024 * 1024 * 2);
  __bf16* Uwb    = (__bf16*)alloc((size_t)1024 * 512 * 2);
  // activations
  __bf16* cat_se  = (__bf16*)alloc((size_t)2048 * 2048 * 2);
  float*  tmp1    = (float*)alloc((size_t)2048 * 2048 * 4);
  __bf16* hq      = (__bf16*)alloc((size_t)2048 * 2048 * 2);   // q_ln / p_ln reuse
  __bf16* qb      = (__bf16*)alloc((size_t)2048 * 256 * 2);
  __bf16* attn    = (__bf16*)alloc((size_t)3 * 2048 * 4096 * 2); // scores->attn, in-place
  __bf16* amb     = (__bf16*)alloc((size_t)3 * 2048 * 1024 * 2);
  __bf16* ctxcat  = (__bf16*)alloc((size_t)2048 * 3072 * 2);
  float*  mix     = (float*)alloc((size_t)2048 * 4 * 4);
  __bf16* cat_cz  = (__bf16*)alloc((size_t)2048 * 2048 * 2);
  __bf16* cat_pc  = (__bf16*)alloc((size_t)2048 * 2048 * 2);
  __bf16* cat_sec = (__bf16*)alloc((size_t)2048 * 3072 * 2);
  __bf16* wpb     = (__bf16*)alloc((size_t)2048 * 512 * 2);
  __bf16* uvtb    = (__bf16*)alloc((size_t)2048 * 128 * 2);
  float*  uv      = (float*)alloc((size_t)2048 * 512 * 4);
  float*  amod    = (float*)alloc((size_t)2048 * 512 * 4);
  float*  wBo     = (float*)alloc((size_t)2048 * 512 * 4);
  __bf16* wtb     = (__bf16*)alloc((size_t)2048 * 512 * 2);
  // late-stage buffers alias the (dead-by-then) attn region: 36 MB < 48 MB.
  // attn is last read by the batched attn@M GEMM; everything below is written
  // strictly after that dispatch in stream order.
  char* arec = (char*)attn;
  float*  hp   = (float*)(arec);                         // 8 MB
  __bf16* ptb  = (__bf16*)(arec + (size_t)8  * 1024 * 1024);  // 4 MB
  float*  gpre = (float*)(arec + (size_t)12 * 1024 * 1024);   // 8 MB
  float*  pu   = (float*)(arec + (size_t)20 * 1024 * 1024);   // 8 MB
  float*  wu   = (float*)(arec + (size_t)28 * 1024 * 1024);   // 8 MB

  auto g128 = [&](const __bf16* Ap, const __bf16* Bp, const float* bias, void* C,
                  int M, int N, int K, int lda, int ldb, int ldc, int bf16o,
                  float sc, int batch, long sA, long sB, long sC) {
    dim3 g(N >> 7, M >> 7, batch);
    gemm_nt<128, 128><<<g, 256, 0, stream>>>(Ap, Bp, bias, C, K, lda, ldb, ldc, bf16o, sc, sA, sB, sC);
  };
  auto g12864 = [&](const __bf16* Ap, const __bf16* Bp, const float* bias, void* C,
                    int M, int N, int K, int lda, int ldb, int ldc, int bf16o) {
    dim3 g(N >> 6, M >> 7, 1);
    gemm_nt<128, 64><<<g, 256, 0, stream>>>(Ap, Bp, bias, C, K, lda, ldb, ldc, bf16o, 1.f, 0, 0, 0);
  };
  auto g64 = [&](const __bf16* Ap, const __bf16* Bp, const float* bias, void* C,
                 int M, int N, int K, int lda, int ldb, int ldc, int bf16o, float sc) {
    dim3 g(N >> 6, M >> 6, 1);
    gemm_nt<64, 64><<<g, 256, 0, stream>>>(Ap, Bp, bias, C, K, lda, ldb, ldc, bf16o, sc, 0, 0, 0);
  };
  auto tconv = [&](const float* s, __bf16* d, int R, int C) {
    dim3 g(C >> 5, R >> 5);
    tconv_kernel<<<g, 256, 0, stream>>>(s, d, R, C);
  };
  auto f2b = [&](const float* s, __bf16* d, int rows, int cols, int sld, int dld) {
    int n = rows * (cols >> 2);
    f2b_kernel<<<(n + 255) / 256, 256, 0, stream>>>(s, d, rows, cols, sld, dld);
  };

  // ---- weight conversions ----
  tconv(Wq1, Wq1t, 2048, 2048);
  tconv(Wq2, Wq2t, 2048, 256);
  f2b(K0, Kb + 0 * 4096 * 256, 1, 4096 * 256, 0, 0);
  f2b(K1, Kb + 1 * 4096 * 256, 1, 4096 * 256, 0, 0);
  f2b(K2, Kb + 2 * 4096 * 256, 1, 4096 * 256, 0, 0);
  tconv(M0, Mt + (size_t)0 * 1024 * 4096, 4096, 1024);
  tconv(M1, Mt + (size_t)1 * 1024 * 4096, 4096, 1024);
  tconv(M2, Mt + (size_t)2 * 1024 * 4096, 4096, 1024);
  tconv(Wl0, Wlt + 0 * 1024 * 1024, 1024, 1024);
  tconv(Wl1, Wlt + 1 * 1024 * 1024, 1024, 1024);
  tconv(Wl2, Wlt + 2 * 1024 * 1024, 1024, 1024);
  tconv(Wz, Wzt, 1024, 1024);
  tconv(A_V, AVt, 512, 128);
  f2b(A_U, AUb, 1, 512 * 128, 0, 0);
  tconv(Wamod, Wamodt, 1024, 512);
  tconv(WB_w, WBt, 2048, 512);
  tconv(Wp1, Wp1t, 2048, 2048);
  tconv(Wp2, Wp2t, 2048, 1024);
  tconv(Wg, Wgt, 3072, 1024);
  f2b(U_p, Upb, 1, 1024 * 1024, 0, 0);
  f2b(U_w, Uwb, 1, 1024 * 512, 0, 0);
  // ---- activation concats ----
  f2b(s_prev, cat_se, 2048, 1024, 1024, 2048);
  f2b(e_t, cat_se + 1024, 2048, 1024, 1024, 2048);
  f2b(p_prev, cat_pc, 2048, 1024, 1024, 2048);
  f2b(s_prev, cat_sec, 2048, 1024, 1024, 3072);
  f2b(e_t, cat_sec + 1024, 2048, 1024, 1024, 3072);
  f2b(w_prev, wpb, 1, 2048 * 512, 0, 0);

  // ---- q path ----
  g128(cat_se, Wq1t, bq1, tmp1, 2048, 2048, 2048, 2048, 2048, 2048, 0, 1.f, 1, 0, 0, 0);
  ln_relu_kernel<<<2048, 256, 0, stream>>>(tmp1, lnq_s, lnq_b, hq, 2048);
  g64(hq, Wq2t, bq2, qb, 2048, 256, 2048, 2048, 2048, 256, 1, 0.0625f);  // 1/sqrt(256) folded

  // ---- CMS levels (batched over grid.z = 3) ----
  g128(qb, Kb, nullptr, attn, 2048, 4096, 256, 256, 256, 4096, 1, 1.f,
       3, 0, (long)4096 * 256, (long)2048 * 4096);
  softmax_bf16_kernel<<<3 * 2048, 256, 0, stream>>>(attn);
  g128(attn, Mt, nullptr, amb, 2048, 1024, 4096, 4096, 4096, 1024, 1, 1.f,
       3, (long)2048 * 4096, (long)1024 * 4096, (long)2048 * 1024);
  // NOTE: attn region is dead after this point (aliased by hp/ptb/gpre/pu/wu)
  g128(amb, Wlt, nullptr, ctxcat, 2048, 1024, 1024, 1024, 1024, 3072, 1, 1.f,
       3, (long)2048 * 1024, (long)1024 * 1024, 1024);
  wmix_kernel<<<2048, 256, 0, stream>>>(ctxcat, Wmix, bmix, mix);
  ct_combine_kernel<<<8192, 256, 0, stream>>>(ctxcat, mix, cat_cz, cat_pc, cat_sec);

  // ---- wave path ----
  g12864(cat_se + 1024, Wzt, bz, cat_cz + 1024, 2048, 1024, 1024, 2048, 1024, 2048, 1);
  g64(wpb, AVt, nullptr, uvtb, 2048, 128, 512, 512, 512, 128, 1, 1.f);
  g64(uvtb, AUb, nullptr, uv, 2048, 512, 128, 128, 128, 512, 0, 1.f);
  g64(cat_cz, Wamodt, bamod, amod, 2048, 512, 1024, 2048, 1024, 512, 0, 1.f);
  g64(cat_cz, WBt, bB, wBo, 2048, 512, 2048, 2048, 2048, 512, 0, 1.f);
  w_combine_kernel<<<4096, 256, 0, stream>>>(w_prev, uv, amod, wBo, A_diag, out_w, wtb);

  // ---- particle path ----
  g128(cat_pc, Wp1t, bp1, tmp1, 2048, 2048, 2048, 2048, 2048, 2048, 0, 1.f, 1, 0, 0, 0);
  ln_relu_kernel<<<2048, 256, 0, stream>>>(tmp1, lnp_s, lnp_b, hq, 2048);
  g12864(hq, Wp2t, bp2, hp, 2048, 1024, 2048, 2048, 2048, 1024, 0);
  p_combine_kernel<<<8192, 256, 0, stream>>>(p_prev, hp, out_p, ptb);

  // ---- gate + final state ----
  g12864(cat_sec, Wgt, bg, gpre, 2048, 1024, 3072, 3072, 3072, 1024, 0);
  g12864(ptb, Upb, nullptr, pu, 2048, 1024, 1024, 1024, 1024, 1024, 0);
  g12864(wtb, Uwb, nullptr, wu, 2048, 1024, 512, 512, 512, 1024, 0);
  s_final_kernel<<<8192, 256, 0, stream>>>(s_prev, gpre, pu, wu, out_s);
}

// Round 3
// 786.239 us; speedup vs baseline: 1.6727x; 1.2201x over previous
//
#include <hip/hip_runtime.h>

typedef __bf16 bf16x8 __attribute__((ext_vector_type(8)));
typedef __bf16 bf16x4 __attribute__((ext_vector_type(4)));
typedef float floatx4 __attribute__((ext_vector_type(4)));

__device__ __forceinline__ void gl_lds16(const __bf16* g, const __bf16* l) {
  __builtin_amdgcn_global_load_lds(
      (const __attribute__((address_space(1))) unsigned int*)g,
      (__attribute__((address_space(3))) unsigned int*)l, 16, 0, 0);
}

// =====================================================================
// GEMM: C[M,N] = A[M,K] bf16 (lda) x Bt[N,K]^T bf16 (ldb) [+bias]*cscale
// blockIdx.z encodes (batch, ksplit): zb = z/nsplit, zs = z%nsplit.
// A/B advance by zb*sA/sB and K-offset zs*Ksub; C slice = z*sC (reduce
// kernel sums the nsplit slices). K arg = Ksub. m97 staging layout.
// =====================================================================
template <int BM, int BN>
__global__ __launch_bounds__(256)
void gemm_nt(const __bf16* __restrict__ A, const __bf16* __restrict__ Bt,
             const float* __restrict__ bias, void* __restrict__ Cv,
             int K, int lda, int ldb, int ldc, int bf16_out, float cscale,
             long sA, long sB, long sC, int nsplit)
{
  constexpr int MI = BM / 32;
  constexpr int NJ = BN / 32;
  __shared__ __align__(16) __bf16 As[BM * 32];
  __shared__ __align__(16) __bf16 Bs[BN * 32];
  const int tid = threadIdx.x;
  const int bm = blockIdx.y * BM, bn = blockIdx.x * BN;
  const int zb = blockIdx.z / nsplit, zs = blockIdx.z % nsplit;
  const __bf16* Ab = A  + (size_t)zb * sA + (size_t)zs * K;
  const __bf16* Bb = Bt + (size_t)zb * sB + (size_t)zs * K;
  const int wave = tid >> 6, lane = tid & 63;
  const int wm = (wave & 1) * (BM / 2), wn = (wave >> 1) * (BN / 2);
  const int lrow = lane & 15, quad = lane >> 4;
  const int srow = tid >> 2, scol = (tid & 3) << 3;

  const __bf16* Ap = Ab + (size_t)(bm + srow) * lda + scol;
  const __bf16* Bp = Bb + (size_t)(bn + srow) * ldb + scol;

  floatx4 acc[MI][NJ];
#pragma unroll
  for (int i = 0; i < MI; ++i)
#pragma unroll
    for (int j = 0; j < NJ; ++j) acc[i][j] = floatx4{0.f, 0.f, 0.f, 0.f};

  for (int k0 = 0; k0 < K; k0 += 32) {
#pragma unroll
    for (int r = 0; r < BM / 64; ++r)
      gl_lds16(Ap + (size_t)(64 * r) * lda + k0, &As[tid * 8 + r * 2048]);
#pragma unroll
    for (int r = 0; r < BN / 64; ++r)
      gl_lds16(Bp + (size_t)(64 * r) * ldb + k0, &Bs[tid * 8 + r * 2048]);
    __syncthreads();
    bf16x8 af[MI], bfr[NJ];
#pragma unroll
    for (int i = 0; i < MI; ++i)
      af[i] = *(const bf16x8*)&As[(wm + i * 16 + lrow) * 32 + (quad << 3)];
#pragma unroll
    for (int j = 0; j < NJ; ++j)
      bfr[j] = *(const bf16x8*)&Bs[(wn + j * 16 + lrow) * 32 + (quad << 3)];
#pragma unroll
    for (int i = 0; i < MI; ++i)
#pragma unroll
      for (int j = 0; j < NJ; ++j)
        acc[i][j] = __builtin_amdgcn_mfma_f32_16x16x32_bf16(af[i], bfr[j], acc[i][j], 0, 0, 0);
    __syncthreads();
  }

  // C/D layout (verified m89/m91): col = lane&15, row = quad*4 + reg
  if (bf16_out) {
    __bf16* C = (__bf16*)Cv + (size_t)blockIdx.z * sC;
#pragma unroll
    for (int i = 0; i < MI; ++i) {
      const int row0 = bm + wm + i * 16 + (quad << 2);
#pragma unroll
      for (int j = 0; j < NJ; ++j) {
        const int col = bn + wn + j * 16 + lrow;
        const float bv = bias ? bias[col] : 0.f;
#pragma unroll
        for (int r = 0; r < 4; ++r)
          C[(size_t)(row0 + r) * ldc + col] = (__bf16)((acc[i][j][r] + bv) * cscale);
      }
    }
  } else {
    float* C = (float*)Cv + (size_t)blockIdx.z * sC;
#pragma unroll
    for (int i = 0; i < MI; ++i) {
      const int row0 = bm + wm + i * 16 + (quad << 2);
#pragma unroll
      for (int j = 0; j < NJ; ++j) {
        const int col = bn + wn + j * 16 + lrow;
        const float bv = bias ? bias[col] : 0.f;
#pragma unroll
        for (int r = 0; r < 4; ++r)
          C[(size_t)(row0 + r) * ldc + col] = (acc[i][j][r] + bv) * cscale;
      }
    }
  }
}

// ---- split-K reduce: out[z*obs + r*ldo + c] = (sum_s part[(z*ns+s)*sC ...] + bias[c]) * scale
__global__ __launch_bounds__(256)
void reduce_kernel(const __bf16* __restrict__ part, __bf16* __restrict__ out,
                   const float* __restrict__ bias, int N, int ldo, long obs,
                   long sC, int nsplit, float scale)
{
  const long idx = ((long)blockIdx.x * 256 + threadIdx.x) * 4;
  const int r = (int)(idx / N), c = (int)(idx % N);
  const __bf16* p0 = part + (size_t)blockIdx.z * nsplit * sC + idx;
  float a0 = 0.f, a1 = 0.f, a2 = 0.f, a3 = 0.f;
  for (int s = 0; s < nsplit; ++s) {
    bf16x4 v = *(const bf16x4*)(p0 + (size_t)s * sC);
    a0 += (float)v[0]; a1 += (float)v[1]; a2 += (float)v[2]; a3 += (float)v[3];
  }
  if (bias) { a0 += bias[c]; a1 += bias[c + 1]; a2 += bias[c + 2]; a3 += bias[c + 3]; }
  bf16x4 o;
  o[0] = (__bf16)(a0 * scale); o[1] = (__bf16)(a1 * scale);
  o[2] = (__bf16)(a2 * scale); o[3] = (__bf16)(a3 * scale);
  *(bf16x4*)(out + (size_t)blockIdx.z * obs + (size_t)r * ldo + c) = o;
}

// ---- batched fp32 [R,C] -> bf16 [C,R] transpose-convert ----
struct TSegs {
  const float* src[16]; __bf16* dst[16];
  int R[16], C[16]; int prefix[17]; int nseg;
};
__global__ __launch_bounds__(256)
void tconv_batch(TSegs t)
{
  __shared__ float tile[32][33];
  int s = 0;
  while (s < t.nseg - 1 && (int)blockIdx.x >= t.prefix[s + 1]) ++s;
  const int local = blockIdx.x - t.prefix[s];
  const int Ct = t.C[s] >> 5;
  const int tr = local / Ct, tc = local - tr * Ct;
  const int r0 = tr << 5, c0 = tc << 5;
  const float* src = t.src[s];
  __bf16* dst = t.dst[s];
  const int R = t.R[s], C = t.C[s];
  const int x = threadIdx.x & 31, y = threadIdx.x >> 5;
#pragma unroll
  for (int i = 0; i < 32; i += 8)
    tile[y + i][x] = src[(size_t)(r0 + y + i) * C + c0 + x];
  __syncthreads();
#pragma unroll
  for (int i = 0; i < 32; i += 8)
    dst[(size_t)(c0 + y + i) * R + r0 + x] = (__bf16)tile[x][y + i];
}

// ---- batched fp32 -> bf16 (strided rows) ----
struct FSegs {
  const float* src[16]; __bf16* dst[16];
  int rows[16], cols[16], sld[16], dld[16]; int prefix[17]; int nseg;
};
__global__ __launch_bounds__(256)
void f2b_batch(FSegs t)
{
  int s = 0;
  while (s < t.nseg - 1 && (int)blockIdx.x >= t.prefix[s + 1]) ++s;
  const long e = ((long)(blockIdx.x - t.prefix[s]) * 256 + threadIdx.x) * 4;
  const int cols = t.cols[s];
  if (e >= (long)t.rows[s] * cols) return;
  const int r = (int)(e / cols), c = (int)(e % cols);
  float4 v = *(const float4*)(t.src[s] + (size_t)r * t.sld[s] + c);
  bf16x4 o;
  o[0] = (__bf16)v.x; o[1] = (__bf16)v.y; o[2] = (__bf16)v.z; o[3] = (__bf16)v.w;
  *(bf16x4*)(t.dst[s] + (size_t)r * t.dld[s] + c) = o;
}

// ---- LayerNorm(+scale,bias)+ReLU, bf16 in/out, cols=2048, 1 block/row ----
__global__ __launch_bounds__(256)
void ln_relu_bf16(const __bf16* __restrict__ x, const float* __restrict__ sc,
                  const float* __restrict__ bi, __bf16* __restrict__ out)
{
  const int row = blockIdx.x;
  const __bf16* xr = x + (size_t)row * 2048;
  __bf16* orow = out + (size_t)row * 2048;
  const int c = threadIdx.x << 3;
  bf16x8 v = *(const bf16x8*)&xr[c];
  float f[8], s = 0.f, ss = 0.f;
#pragma unroll
  for (int i = 0; i < 8; ++i) { f[i] = (float)v[i]; s += f[i]; ss += f[i] * f[i]; }
  __shared__ float shs[4], shss[4];
  const int lane = threadIdx.x & 63, w = threadIdx.x >> 6;
  for (int o = 32; o; o >>= 1) { s += __shfl_down(s, o, 64); ss += __shfl_down(ss, o, 64); }
  if (!lane) { shs[w] = s; shss[w] = ss; }
  __syncthreads();
  const float fs = shs[0] + shs[1] + shs[2] + shs[3];
  const float fss = shss[0] + shss[1] + shss[2] + shss[3];
  const float mu = fs * (1.f / 2048.f);
  const float rstd = rsqrtf(fss * (1.f / 2048.f) - mu * mu + 1e-6f);
  bf16x8 o;
#pragma unroll
  for (int i = 0; i < 8; ++i)
    o[i] = (__bf16)fmaxf((f[i] - mu) * rstd * sc[c + i] + bi[c + i], 0.f);
  *(bf16x8*)&orow[c] = o;
}

// ---- in-place row softmax on bf16, cols=4096 ----
__global__ __launch_bounds__(256)
void softmax_bf16_kernel(__bf16* __restrict__ x)
{
  __bf16* xr = x + (size_t)blockIdx.x * 4096;
  bf16x8 v0 = *(const bf16x8*)&xr[threadIdx.x * 16];
  bf16x8 v1 = *(const bf16x8*)&xr[threadIdx.x * 16 + 8];
  float f[16];
#pragma unroll
  for (int i = 0; i < 8; ++i) { f[i] = (float)v0[i]; f[i + 8] = (float)v1[i]; }
  float m = f[0];
#pragma unroll
  for (int i = 1; i < 16; ++i) m = fmaxf(m, f[i]);
  __shared__ float sh[4];
  const int lane = threadIdx.x & 63, w = threadIdx.x >> 6;
  for (int o = 32; o; o >>= 1) m = fmaxf(m, __shfl_down(m, o, 64));
  if (!lane) sh[w] = m;
  __syncthreads();
  m = fmaxf(fmaxf(sh[0], sh[1]), fmaxf(sh[2], sh[3]));
  __syncthreads();
  float s = 0.f;
#pragma unroll
  for (int i = 0; i < 16; ++i) { f[i] = expf(f[i] - m); s += f[i]; }
  for (int o = 32; o; o >>= 1) s += __shfl_down(s, o, 64);
  if (!lane) sh[w] = s;
  __syncthreads();
  const float rs = 1.f / (sh[0] + sh[1] + sh[2] + sh[3]);
  bf16x8 o0, o1;
#pragma unroll
  for (int i = 0; i < 8; ++i) { o0[i] = (__bf16)(f[i] * rs); o1[i] = (__bf16)(f[i + 8] * rs); }
  *(bf16x8*)&xr[threadIdx.x * 16] = o0;
  *(bf16x8*)&xr[threadIdx.x * 16 + 8] = o1;
}

// ---- mix = softmax(ctx_cat @ Wmix + bmix) ----
__global__ __launch_bounds__(256)
void wmix_kernel(const __bf16* __restrict__ ctx, const float* __restrict__ Wm,
                 const float* __restrict__ bm, float* __restrict__ mix)
{
  const int row = blockIdx.x;
  const __bf16* cr = ctx + (size_t)row * 3072;
  float a0 = 0.f, a1 = 0.f, a2 = 0.f;
  for (int c = threadIdx.x; c < 3072; c += 256) {
    float v = (float)cr[c];
    a0 = fmaf(v, Wm[c * 3 + 0], a0);
    a1 = fmaf(v, Wm[c * 3 + 1], a1);
    a2 = fmaf(v, Wm[c * 3 + 2], a2);
  }
  __shared__ float sh[3][4];
  const int lane = threadIdx.x & 63, w = threadIdx.x >> 6;
  for (int o = 32; o; o >>= 1) {
    a0 += __shfl_down(a0, o, 64); a1 += __shfl_down(a1, o, 64); a2 += __shfl_down(a2, o, 64);
  }
  if (!lane) { sh[0][w] = a0; sh[1][w] = a1; sh[2][w] = a2; }
  __syncthreads();
  if (threadIdx.x == 0) {
    float l0 = sh[0][0] + sh[0][1] + sh[0][2] + sh[0][3] + bm[0];
    float l1 = sh[1][0] + sh[1][1] + sh[1][2] + sh[1][3] + bm[1];
    float l2 = sh[2][0] + sh[2][1] + sh[2][2] + sh[2][3] + bm[2];
    float mm = fmaxf(l0, fmaxf(l1, l2));
    float e0 = expf(l0 - mm), e1 = expf(l1 - mm), e2 = expf(l2 - mm);
    float rs = 1.f / (e0 + e1 + e2);
    mix[row * 4 + 0] = e0 * rs; mix[row * 4 + 1] = e1 * rs; mix[row * 4 + 2] = e2 * rs;
  }
}

// ---- c_t -> 3 concat buffers ----
__global__ __launch_bounds__(256)
void ct_combine_kernel(const __bf16* __restrict__ ctx, const float* __restrict__ mix,
                       __bf16* __restrict__ cz, __bf16* __restrict__ pc,
                       __bf16* __restrict__ sec)
{
  const int idx = blockIdx.x * 256 + threadIdx.x;
  const int row = idx >> 10, d = idx & 1023;
  const __bf16* cr = ctx + (size_t)row * 3072 + d;
  const float v = mix[row * 4 + 0] * (float)cr[0] +
                  mix[row * 4 + 1] * (float)cr[1024] +
                  mix[row * 4 + 2] * (float)cr[2048];
  const __bf16 b = (__bf16)v;
  cz[(size_t)row * 2048 + d] = b;
  pc[(size_t)row * 2048 + 1024 + d] = b;
  sec[(size_t)row * 3072 + 2048 + d] = b;
}

__global__ __launch_bounds__(256)
void w_combine_kernel(const float* __restrict__ w_prev, const float* __restrict__ uv,
                      const float* __restrict__ amod, const float* __restrict__ wB,
                      const float* __restrict__ A_diag, float* __restrict__ w_out,
                      __bf16* __restrict__ w_bf)
{
  const int idx = blockIdx.x * 256 + threadIdx.x;
  const int d = idx & 511;
  const float Ad = tanhf(A_diag[d]) * 0.9f;
  const float wl = fmaf(Ad, w_prev[idx], uv[idx]);
  const float w = fmaf(tanhf(amod[idx]), wl, wB[idx]);
  w_out[idx] = w;
  w_bf[idx] = (__bf16)w;
}

__global__ __launch_bounds__(256)
void p_combine_kernel(const float* __restrict__ p_prev, const __bf16* __restrict__ hp,
                      float* __restrict__ p_out, __bf16* __restrict__ p_bf)
{
  const int idx = blockIdx.x * 256 + threadIdx.x;
  const float p = p_prev[idx] + (float)hp[idx];
  p_out[idx] = p;
  p_bf[idx] = (__bf16)p;
}

__global__ __launch_bounds__(256)
void s_final_kernel(const float* __restrict__ s_prev, const __bf16* __restrict__ gpre,
                    const float* __restrict__ pu, const float* __restrict__ wu,
                    float* __restrict__ s_out)
{
  const int idx = blockIdx.x * 256 + threadIdx.x;
  const float g = 1.f / (1.f + expf(-(float)gpre[idx]));
  float s = s_prev[idx] + g * pu[idx] + (1.f - g) * wu[idx];
  s = fminf(fmaxf(s, -10.f), 10.f);
  s_out[idx] = s;
}

// =====================================================================
extern "C" void kernel_launch(void* const* d_in, const int* in_sizes, int n_in,
                              void* d_out, int out_size, void* d_ws, size_t ws_size,
                              hipStream_t stream)
{
  const float* s_prev = (const float*)d_in[0];
  const float* w_prev = (const float*)d_in[1];
  const float* p_prev = (const float*)d_in[2];
  const float* e_t    = (const float*)d_in[3];
  const float* M0 = (const float*)d_in[4];
  const float* M1 = (const float*)d_in[5];
  const float* M2 = (const float*)d_in[6];
  const float* K0 = (const float*)d_in[7];
  const float* K1 = (const float*)d_in[8];
  const float* K2 = (const float*)d_in[9];
  const float* Wq1 = (const float*)d_in[10];
  const float* bq1 = (const float*)d_in[11];
  const float* lnq_s = (const float*)d_in[12];
  const float* lnq_b = (const float*)d_in[13];
  const float* Wq2 = (const float*)d_in[14];
  const float* bq2 = (const float*)d_in[15];
  const float* Wl0 = (const float*)d_in[16];
  const float* Wl1 = (const float*)d_in[17];
  const float* Wl2 = (const float*)d_in[18];
  const float* Wmix = (const float*)d_in[19];
  const float* bmix = (const float*)d_in[20];
  const float* Wz = (const float*)d_in[21];
  const float* bz = (const float*)d_in[22];
  const float* A_diag = (const float*)d_in[23];
  const float* A_U = (const float*)d_in[24];
  const float* A_V = (const float*)d_in[25];
  const float* Wamod = (const float*)d_in[26];
  const float* bamod = (const float*)d_in[27];
  const float* WB_w = (const float*)d_in[28];
  const float* bB = (const float*)d_in[29];
  const float* Wp1 = (const float*)d_in[30];
  const float* bp1 = (const float*)d_in[31];
  const float* lnp_s = (const float*)d_in[32];
  const float* lnp_b = (const float*)d_in[33];
  const float* Wp2 = (const float*)d_in[34];
  const float* bp2 = (const float*)d_in[35];
  const float* Wg = (const float*)d_in[36];
  const float* bg = (const float*)d_in[37];
  const float* U_p = (const float*)d_in[38];
  const float* U_w = (const float*)d_in[39];

  float* out_s = (float*)d_out;
  float* out_w = out_s + 2048 * 1024;
  float* out_p = out_w + 2048 * 512;

  char* base = (char*)d_ws;
  size_t off = 0;
  auto alloc = [&](size_t n) -> void* {
    void* p = base + off;
    off = (off + n + 255) & ~(size_t)255;
    return p;
  };

  // bf16 weights ([N,K]) ~71 MB
  __bf16* Wq1t   = (__bf16*)alloc((size_t)2048 * 2048 * 2);
  __bf16* Wq2t   = (__bf16*)alloc((size_t)256 * 2048 * 2);
  __bf16* Kb     = (__bf16*)alloc((size_t)3 * 4096 * 256 * 2);
  __bf16* Mt     = (__bf16*)alloc((size_t)3 * 1024 * 4096 * 2);
  __bf16* Wlt    = (__bf16*)alloc((size_t)3 * 1024 * 1024 * 2);
  __bf16* Wzt    = (__bf16*)alloc((size_t)1024 * 1024 * 2);
  __bf16* AVt    = (__bf16*)alloc((size_t)128 * 512 * 2);
  __bf16* AUb    = (__bf16*)alloc((size_t)512 * 128 * 2);
  __bf16* Wamodt = (__bf16*)alloc((size_t)512 * 1024 * 2);
  __bf16* WBt    = (__bf16*)alloc((size_t)512 * 2048 * 2);
  __bf16* Wp1t   = (__bf16*)alloc((size_t)2048 * 2048 * 2);
  __bf16* Wp2t   = (__bf16*)alloc((size_t)1024 * 2048 * 2);
  __bf16* Wgt    = (__bf16*)alloc((size_t)1024 * 3072 * 2);
  __bf16* Upb    = (__bf16*)alloc((size_t)1024 * 1024 * 2);
  __bf16* Uwb    = (__bf16*)alloc((size_t)1024 * 512 * 2);
  // split-K partial scratch (max: 6 x 2048x1024 bf16 = 25 MB)
  __bf16* P      = (__bf16*)alloc((size_t)6 * 2048 * 1024 * 2);
  // activations
  __bf16* cat_se  = (__bf16*)alloc((size_t)2048 * 2048 * 2);
  __bf16* tmp1b   = (__bf16*)alloc((size_t)2048 * 2048 * 2);
  __bf16* hq      = (__bf16*)alloc((size_t)2048 * 2048 * 2);
  __bf16* qb      = (__bf16*)alloc((size_t)2048 * 256 * 2);
  __bf16* attn    = (__bf16*)alloc((size_t)3 * 2048 * 4096 * 2);
  __bf16* amb     = (__bf16*)alloc((size_t)3 * 2048 * 1024 * 2);
  __bf16* ctxcat  = (__bf16*)alloc((size_t)2048 * 3072 * 2);
  float*  mix     = (float*)alloc((size_t)2048 * 4 * 4);
  __bf16* cat_cz  = (__bf16*)alloc((size_t)2048 * 2048 * 2);
  __bf16* cat_pc  = (__bf16*)alloc((size_t)2048 * 2048 * 2);
  __bf16* cat_sec = (__bf16*)alloc((size_t)2048 * 3072 * 2);
  __bf16* wpb     = (__bf16*)alloc((size_t)2048 * 512 * 2);
  __bf16* uvtb    = (__bf16*)alloc((size_t)2048 * 128 * 2);
  float*  uv      = (float*)alloc((size_t)2048 * 512 * 4);
  float*  amod    = (float*)alloc((size_t)2048 * 512 * 4);
  float*  wBo     = (float*)alloc((size_t)2048 * 512 * 4);
  __bf16* wtb     = (__bf16*)alloc((size_t)2048 * 512 * 2);
  // late buffers alias the attn region (dead after the attn@M GEMM reads it)
  char* arec = (char*)attn;
  __bf16* hp   = (__bf16*)(arec);                               // 4 MB
  __bf16* ptb  = (__bf16*)(arec + (size_t)4  * 1024 * 1024);    // 4 MB
  __bf16* gpre = (__bf16*)(arec + (size_t)8  * 1024 * 1024);    // 4 MB
  float*  pu   = (float*)(arec + (size_t)12 * 1024 * 1024);     // 8 MB
  float*  wu   = (float*)(arec + (size_t)20 * 1024 * 1024);     // 8 MB

  auto gemm = [&](auto tag, const __bf16* Ap, const __bf16* Bp, const float* bias,
                  void* C, int M, int N, int Ksub, int lda, int ldb, int ldc,
                  int bf16o, float sc, int batch, int nsplit, long sA, long sB, long sC) {
    constexpr int BM = decltype(tag)::value >> 16, BN = decltype(tag)::value & 0xffff;
    dim3 g(N / BN, M / BM, batch * nsplit);
    gemm_nt<BM, BN><<<g, 256, 0, stream>>>(Ap, Bp, bias, C, Ksub, lda, ldb, ldc,
                                           bf16o, sc, sA, sB, sC, nsplit);
  };
  auto reduce = [&](const __bf16* part, __bf16* out, const float* bias, int M, int N,
                    int ldo, long obs, long sC, int nsplit, float sc, int batch) {
    dim3 g((unsigned)((long)M * N / 1024), 1, batch);
    reduce_kernel<<<g, 256, 0, stream>>>(part, out, bias, N, ldo, obs, sC, nsplit, sc);
  };
  using T128 = std::integral_constant<int, (128 << 16) | 128>;
  using T12864 = std::integral_constant<int, (128 << 16) | 64>;
  using T64 = std::integral_constant<int, (64 << 16) | 64>;

  // ---- batched weight transpose-conversions (15 segs) ----
  {
    TSegs t{};
    const float* s[15] = {Wq1, Wq2, M0, M1, M2, Wl0, Wl1, Wl2, Wz, A_V, Wamod,
                          WB_w, Wp1, Wp2, Wg};
    __bf16* d[15] = {Wq1t, Wq2t, Mt, Mt + (size_t)1024 * 4096, Mt + (size_t)2048 * 4096,
                     Wlt, Wlt + 1024 * 1024, Wlt + 2 * 1024 * 1024, Wzt, AVt, Wamodt,
                     WBt, Wp1t, Wp2t, Wgt};
    int R[15] = {2048, 2048, 4096, 4096, 4096, 1024, 1024, 1024, 1024, 512, 1024,
                 2048, 2048, 2048, 3072};
    int C[15] = {2048, 256, 1024, 1024, 1024, 1024, 1024, 1024, 1024, 128, 512,
                 512, 2048, 1024, 1024};
    int p = 0;
    for (int i = 0; i < 15; ++i) {
      t.src[i] = s[i]; t.dst[i] = d[i]; t.R[i] = R[i]; t.C[i] = C[i];
      t.prefix[i] = p; p += (R[i] >> 5) * (C[i] >> 5);
    }
    t.prefix[15] = p; t.nseg = 15;
    tconv_batch<<<p, 256, 0, stream>>>(t);
  }
  // ---- batched flat/strided fp32->bf16 (12 segs) ----
  {
    FSegs t{};
    const float* s[12] = {K0, K1, K2, A_U, U_p, U_w, s_prev, e_t, p_prev,
                          s_prev, e_t, w_prev};
    __bf16* d[12] = {Kb, Kb + 4096 * 256, Kb + 2 * 4096 * 256, AUb, Upb, Uwb,
                     cat_se, cat_se + 1024, cat_pc, cat_sec, cat_sec + 1024, wpb};
    int rows[12] = {1, 1, 1, 1, 1, 1, 2048, 2048, 2048, 2048, 2048, 1};
    int cols[12] = {4096 * 256, 4096 * 256, 4096 * 256, 512 * 128, 1024 * 1024,
                    1024 * 512, 1024, 1024, 1024, 1024, 1024, 2048 * 512};
    int sld[12] = {0, 0, 0, 0, 0, 0, 1024, 1024, 1024, 1024, 1024, 0};
    int dld[12] = {0, 0, 0, 0, 0, 0, 2048, 2048, 2048, 3072, 3072, 0};
    int p = 0;
    for (int i = 0; i < 12; ++i) {
      t.src[i] = s[i]; t.dst[i] = d[i]; t.rows[i] = rows[i]; t.cols[i] = cols[i];
      t.sld[i] = sld[i] ? sld[i] : cols[i]; t.dld[i] = dld[i] ? dld[i] : cols[i];
      t.prefix[i] = p;
      p += (int)(((long)rows[i] * cols[i] / 4 + 255) / 256);
    }
    t.prefix[12] = p; t.nseg = 12;
    f2b_batch<<<p, 256, 0, stream>>>(t);
  }

  // ---- q path ----
  gemm(T128{}, cat_se, Wq1t, nullptr, P, 2048, 2048, 1024, 2048, 2048, 2048, 1, 1.f,
       1, 2, 0, 0, (long)2048 * 2048);
  reduce(P, tmp1b, bq1, 2048, 2048, 2048, 0, (long)2048 * 2048, 2, 1.f, 1);
  ln_relu_bf16<<<2048, 256, 0, stream>>>(tmp1b, lnq_s, lnq_b, hq);
  gemm(T64{}, hq, Wq2t, nullptr, P, 2048, 256, 512, 2048, 2048, 256, 1, 1.f,
       1, 4, 0, 0, (long)2048 * 256);
  reduce(P, qb, bq2, 2048, 256, 256, 0, (long)2048 * 256, 4, 0.0625f, 1);

  // ---- CMS levels (batched z=3) ----
  gemm(T128{}, qb, Kb, nullptr, attn, 2048, 4096, 256, 256, 256, 4096, 1, 1.f,
       3, 1, 0, (long)4096 * 256, (long)2048 * 4096);
  softmax_bf16_kernel<<<3 * 2048, 256, 0, stream>>>(attn);
  gemm(T128{}, attn, Mt, nullptr, P, 2048, 1024, 2048, 4096, 4096, 1024, 1, 1.f,
       3, 2, (long)2048 * 4096, (long)1024 * 4096, (long)2048 * 1024);
  reduce(P, amb, nullptr, 2048, 1024, 1024, (long)2048 * 1024, (long)2048 * 1024, 2, 1.f, 3);
  // attn region is dead from here (aliased by hp/ptb/gpre/pu/wu)
  gemm(T128{}, amb, Wlt, nullptr, P, 2048, 1024, 512, 1024, 1024, 1024, 1, 1.f,
       3, 2, (long)2048 * 1024, (long)1024 * 1024, (long)2048 * 1024);
  reduce(P, ctxcat, nullptr, 2048, 1024, 3072, 1024, (long)2048 * 1024, 2, 1.f, 3);
  wmix_kernel<<<2048, 256, 0, stream>>>(ctxcat, Wmix, bmix, mix);
  ct_combine_kernel<<<8192, 256, 0, stream>>>(ctxcat, mix, cat_cz, cat_pc, cat_sec);

  // ---- wave path ----
  gemm(T12864{}, cat_se + 1024, Wzt, bz, cat_cz + 1024, 2048, 1024, 1024, 2048, 1024,
       2048, 1, 1.f, 1, 1, 0, 0, 0);
  gemm(T64{}, wpb, AVt, nullptr, uvtb, 2048, 128, 512, 512, 512, 128, 1, 1.f,
       1, 1, 0, 0, 0);
  gemm(T64{}, uvtb, AUb, nullptr, uv, 2048, 512, 128, 128, 128, 512, 0, 1.f,
       1, 1, 0, 0, 0);
  gemm(T64{}, cat_cz, Wamodt, bamod, amod, 2048, 512, 1024, 2048, 1024, 512, 0, 1.f,
       1, 1, 0, 0, 0);
  gemm(T64{}, cat_cz, WBt, bB, wBo, 2048, 512, 2048, 2048, 2048, 512, 0, 1.f,
       1, 1, 0, 0, 0);
  w_combine_kernel<<<4096, 256, 0, stream>>>(w_prev, uv, amod, wBo, A_diag, out_w, wtb);

  // ---- particle path ----
  gemm(T128{}, cat_pc, Wp1t, nullptr, P, 2048, 2048, 1024, 2048, 2048, 2048, 1, 1.f,
       1, 2, 0, 0, (long)2048 * 2048);
  reduce(P, tmp1b, bp1, 2048, 2048, 2048, 0, (long)2048 * 2048, 2, 1.f, 1);
  ln_relu_bf16<<<2048, 256, 0, stream>>>(tmp1b, lnp_s, lnp_b, hq);
  gemm(T128{}, hq, Wp2t, nullptr, P, 2048, 1024, 512, 2048, 2048, 1024, 1, 1.f,
       1, 4, 0, 0, (long)2048 * 1024);
  reduce(P, hp, bp2, 2048, 1024, 1024, 0, (long)2048 * 1024, 4, 1.f, 1);
  p_combine_kernel<<<8192, 256, 0, stream>>>(p_prev, hp, out_p, ptb);

  // ---- gate + final ----
  gemm(T128{}, cat_sec, Wgt, nullptr, P, 2048, 1024, 768, 3072, 3072, 1024, 1, 1.f,
       1, 4, 0, 0, (long)2048 * 1024);
  reduce(P, gpre, bg, 2048, 1024, 1024, 0, (long)2048 * 1024, 4, 1.f, 1);
  gemm(T12864{}, ptb, Upb, nullptr, pu, 2048, 1024, 1024, 1024, 1024, 1024, 0, 1.f,
       1, 1, 0, 0, 0);
  gemm(T12864{}, wtb, Uwb, nullptr, wu, 2048, 1024, 512, 512, 512, 1024, 0, 1.f,
       1, 1, 0, 0, 0);
  s_final_kernel<<<8192, 256, 0, stream>>>(s_prev, gpre, pu, wu, out_s);
}